// Round 9
// baseline (119.476 us; speedup 1.0000x reference)
//
#include <hip/hip_runtime.h>

// ---------------------------------------------------------------------------
// MultiHeadAttentionWindow: B=8 K=4000 D=256 H=8 DQ=DV=32 WIN=200 PAD=50 STEP=100
// Pipeline (batch chunk bc from ws_size):
//   prep_weights : Wt[n][k] = bf16(W[k][n]) for Wq,Wk,Wv,Wo   (once)
//   per chunk:
//     proj_gemm  : merged q/k/v projections (grid.y = mode 0/1/2)
//     fill_edges : replicate-pad edges, zero tails
//     attn_win   : causal cauchy softmax windows, rows 50..149
//     out_gemm   : out = ao @ Wo + bo (fp32)
// Round-9 GEMM: "B-in-regs" — K=256 is small, so:
//   - per wave: B slice (64 n-cols x 256 k) loaded ONCE into 128 VGPR
//   - A tile (64x256) staged ONCE into LDS, k-chunk-major [c][row] pitch 1040B
//     (reads 2-way = b128 floor, writes conflict-free)
//   - K-loop: 32 ds_read + 128 MFMA per wave, ZERO barriers / global loads
//   Fixes r7/r8's latency-bound per-iter stage chain (all pipes <10% busy).
// ---------------------------------------------------------------------------

typedef __bf16 bf16_t;
typedef __bf16 bf16x8 __attribute__((ext_vector_type(8)));
typedef float  f32x4  __attribute__((ext_vector_type(4)));

#define MFMA16(a, b, c) __builtin_amdgcn_mfma_f32_16x16x32_bf16((a), (b), (c), 0, 0, 0)

static __device__ __forceinline__ bf16x8 cvt8(float4 a, float4 b) {
  bf16x8 r;
  r[0] = (bf16_t)a.x; r[1] = (bf16_t)a.y; r[2] = (bf16_t)a.z; r[3] = (bf16_t)a.w;
  r[4] = (bf16_t)b.x; r[5] = (bf16_t)b.y; r[6] = (bf16_t)b.z; r[7] = (bf16_t)b.w;
  return r;
}

static __device__ __forceinline__ unsigned short bbits(bf16_t v) {
  union { bf16_t b; unsigned short u; } c; c.b = v; return c.u;
}

// ---- weight transpose + bf16 convert: Wt[n][k] = bf16(W[k][n]), 4 matrices ----
__global__ __launch_bounds__(256)
void prep_weights(const float* __restrict__ Wq, const float* __restrict__ Wk,
                  const float* __restrict__ Wv, const float* __restrict__ Wo,
                  bf16_t* __restrict__ wt) {
  const int mat  = blockIdx.x >> 6;
  const int tile = blockIdx.x & 63;
  const int kt = (tile >> 3) * 32, nt = (tile & 7) * 32;
  const float* W = (mat == 0) ? Wq : (mat == 1) ? Wk : (mat == 2) ? Wv : Wo;
  __shared__ float t[32][33];
  const int tx = threadIdx.x & 31, ty = threadIdx.x >> 5;  // ty 0..7
#pragma unroll
  for (int i = 0; i < 32; i += 8)
    t[ty + i][tx] = W[(size_t)(kt + ty + i) * 256 + nt + tx];
  __syncthreads();
  bf16_t* dst = wt + (size_t)mat * 65536;
#pragma unroll
  for (int i = 0; i < 32; i += 8)
    dst[(size_t)(nt + ty + i) * 256 + kt + tx] = (bf16_t)t[tx][ty + i];
}

// A-tile LDS geometry: 32 k-chunks (8 bf16 each) x 64 rows, chunk pitch 1040 B.
// frag(kk,hi,mi,lo) at (kk*4+hi)*1040 + (mi*16+lo)*16.
#define LDSA_BYTES (32 * 1040)

// ---- merged projection GEMM: [M x 256] x [256 x 256] + bias ----
// grid (mblk, 3); mode = blockIdx.y: 0 -> qb (row-major, *qscale),
// 1 -> kb (rows b*4064+t+50), 2 -> vt (transposed [bh*32+dv][p]).
// Block: 64 rows x 256 cols, 4 waves; wave = all 64 rows x 64-col slice.
__global__ __launch_bounds__(256, 2)
void proj_gemm(const float* __restrict__ qx, const float* __restrict__ kx,
               const float* __restrict__ vx, const bf16_t* __restrict__ wt,
               const float* __restrict__ bq, const float* __restrict__ bk,
               const float* __restrict__ bv,
               bf16_t* __restrict__ qb, bf16_t* __restrict__ kb,
               bf16_t* __restrict__ vt, int M, float qscale) {
  const int mode = blockIdx.y;
  const float* X    = (mode == 0) ? qx : (mode == 1) ? kx : vx;
  const float* bias = (mode == 0) ? bq : (mode == 1) ? bk : bv;
  const bf16_t* W   = wt + (size_t)mode * 65536;

  __shared__ __align__(16) char lds_a[LDSA_BYTES];
  const int tid  = threadIdx.x;
  const int lane = tid & 63;
  const int wv   = tid >> 6;        // 0..3: wave n-slice (wn = wv*64)
  const int lo   = lane & 15, hi = lane >> 4;
  const int m0   = blockIdx.x * 64;
  const int r    = tid >> 2;        // staging row 0..63
  const int q    = tid & 3;         // staging quad
  int ar = m0 + r; if (ar >= M) ar = M - 1;

  // B slice into registers (once; W is L2-hot 128KB). [kk][ni], 128 VGPR.
  bf16x8 breg[8][4];
#pragma unroll
  for (int kk = 0; kk < 8; ++kk)
#pragma unroll
    for (int ni = 0; ni < 4; ++ni)
      breg[kk][ni] =
          *(const bf16x8*)&W[(size_t)(wv * 64 + ni * 16 + lo) * 256 + kk * 32 + hi * 8];

  // stage A (64x256 fp32 -> bf16) once, k-chunk-major
#pragma unroll
  for (int i = 0; i < 8; ++i) {
    const int c = q * 8 + i;        // k-chunk 0..31 (8 bf16 = 32B fp32)
    const float* ap = X + (size_t)ar * 256 + c * 8;
    const bf16x8 v = cvt8(((const float4*)ap)[0], ((const float4*)ap)[1]);
    *(bf16x8*)(lds_a + c * 1040 + r * 16) = v;
  }
  __syncthreads();

  // K-loop: no barriers, no staging — 32 ds_read + 128 MFMA
  f32x4 acc[4][4] = {};
#pragma unroll
  for (int kk = 0; kk < 8; ++kk) {
    bf16x8 af[4];
#pragma unroll
    for (int mi = 0; mi < 4; ++mi)
      af[mi] = *(const bf16x8*)(lds_a + (kk * 4 + hi) * 1040 + (mi * 16 + lo) * 16);
#pragma unroll
    for (int mi = 0; mi < 4; ++mi)
#pragma unroll
      for (int ni = 0; ni < 4; ++ni)
        acc[mi][ni] = MFMA16(af[mi], breg[kk][ni], acc[mi][ni]);
  }

  // epilogue: C/D layout col = lane&15, row = (lane>>4)*4 + r  [m89-verified]
#pragma unroll
  for (int mi = 0; mi < 4; ++mi) {
    const int mb = m0 + mi * 16 + hi * 4;   // 4-aligned; M % 4 == 0
    if (mb >= M) continue;
#pragma unroll
    for (int ni = 0; ni < 4; ++ni) {
      const int n = wv * 64 + ni * 16 + lo;
      const float bia = bias[n];
      if (mode == 0) {
#pragma unroll
        for (int rr = 0; rr < 4; ++rr)
          qb[(size_t)(mb + rr) * 256 + n] = (bf16_t)((acc[mi][ni][rr] + bia) * qscale);
      } else if (mode == 1) {
        const int b = mb / 4000, t = mb - b * 4000;
#pragma unroll
        for (int rr = 0; rr < 4; ++rr)
          kb[((size_t)b * 4064 + t + 50 + rr) * 256 + n] = (bf16_t)(acc[mi][ni][rr] + bia);
      } else {
        const int b = mb / 4000, t = mb - b * 4000;
        const int h = n >> 5, dv = n & 31;
        bf16_t* O = vt + ((size_t)((b * 8 + h) * 32 + dv)) * 4064 + t + 50;
        unsigned short e0 = bbits((bf16_t)(acc[mi][ni][0] + bia));
        unsigned short e1 = bbits((bf16_t)(acc[mi][ni][1] + bia));
        unsigned short e2 = bbits((bf16_t)(acc[mi][ni][2] + bia));
        unsigned short e3 = bbits((bf16_t)(acc[mi][ni][3] + bia));
        unsigned* O32 = (unsigned*)O;       // (t+50) even -> 4B aligned
        O32[0] = (unsigned)e0 | ((unsigned)e1 << 16);
        O32[1] = (unsigned)e2 | ((unsigned)e3 << 16);
      }
    }
  }
}

// ---- output GEMM: ao[M x 256] (bf16) x Wo^T + bo -> fp32 out ----
__global__ __launch_bounds__(256, 2)
void out_gemm(const bf16_t* __restrict__ ao, const bf16_t* __restrict__ wt,
              const float* __restrict__ bias, float* __restrict__ Out, int M) {
  __shared__ __align__(16) char lds_a[LDSA_BYTES];
  const int tid  = threadIdx.x;
  const int lane = tid & 63;
  const int wv   = tid >> 6;
  const int lo   = lane & 15, hi = lane >> 4;
  const int m0   = blockIdx.x * 64;
  const int r    = tid >> 2;
  const int q    = tid & 3;
  int ar = m0 + r; if (ar >= M) ar = M - 1;

  bf16x8 breg[8][4];
#pragma unroll
  for (int kk = 0; kk < 8; ++kk)
#pragma unroll
    for (int ni = 0; ni < 4; ++ni)
      breg[kk][ni] =
          *(const bf16x8*)&wt[(size_t)(wv * 64 + ni * 16 + lo) * 256 + kk * 32 + hi * 8];

#pragma unroll
  for (int i = 0; i < 8; ++i) {
    const int c = q * 8 + i;
    const bf16x8 v = *(const bf16x8*)&ao[(size_t)ar * 256 + c * 8];
    *(bf16x8*)(lds_a + c * 1040 + r * 16) = v;
  }
  __syncthreads();

  f32x4 acc[4][4] = {};
#pragma unroll
  for (int kk = 0; kk < 8; ++kk) {
    bf16x8 af[4];
#pragma unroll
    for (int mi = 0; mi < 4; ++mi)
      af[mi] = *(const bf16x8*)(lds_a + (kk * 4 + hi) * 1040 + (mi * 16 + lo) * 16);
#pragma unroll
    for (int mi = 0; mi < 4; ++mi)
#pragma unroll
      for (int ni = 0; ni < 4; ++ni)
        acc[mi][ni] = MFMA16(af[mi], breg[kk][ni], acc[mi][ni]);
  }

#pragma unroll
  for (int mi = 0; mi < 4; ++mi) {
    const int mb = m0 + mi * 16 + hi * 4;
    if (mb >= M) continue;
#pragma unroll
    for (int ni = 0; ni < 4; ++ni) {
      const int n = wv * 64 + ni * 16 + lo;
      const float bia = bias[n];
#pragma unroll
      for (int rr = 0; rr < 4; ++rr)
        Out[(size_t)(mb + rr) * 256 + n] = acc[mi][ni][rr] + bia;
    }
  }
}

// ---- fill replicate-pad edges + zero tails for kb and vt (nb batches) ----
__global__ void fill_edges(bf16_t* __restrict__ kb, bf16_t* __restrict__ vt, int nb) {
  const int idx = blockIdx.x * 256 + threadIdx.x;
  const int kcnt = nb * 64 * 256;
  if (idx < kcnt) {                    // kb: [nb][4064][256]
    const int b  = idx >> 14;
    const int pp = (idx >> 8) & 63;    // 0..63
    const int nn = idx & 255;
    const int p  = (pp < 50) ? pp : pp + 4000;   // [0,50) and [4050,4064)
    bf16_t v = (pp < 50) ? kb[((size_t)b * 4064 + 50) * 256 + nn] : (bf16_t)0.f;
    kb[((size_t)b * 4064 + p) * 256 + nn] = v;
  } else {                             // vt: [nb*8][32][4064]
    const int j  = idx - kcnt;
    const int bh = j >> 11;
    const int dv = (j >> 6) & 31;
    const int pp = j & 63;
    const int p  = (pp < 50) ? pp : pp + 4000;
    bf16_t v = (pp < 50) ? vt[((size_t)bh * 32 + dv) * 4064 + 50] : (bf16_t)0.f;
    vt[((size_t)bh * 32 + dv) * 4064 + p] = v;
  }
}

// ---- windowed attention: one block per (b',h,window), 7 waves = 7 row-strips ----
// Chunked: per 32-col chunk {2x QK MFMA -> exp -> 16x32 LDS bounce -> PV 3 MFMA}.
// No cross-lane ops, no barriers; denom via E@ones; normalize after PV.
__global__ __launch_bounds__(448)
void attn_win(const bf16_t* __restrict__ qb, const bf16_t* __restrict__ kb,
              const bf16_t* __restrict__ vt, bf16_t* __restrict__ ao) {
  const int blk = blockIdx.x;
  const int n = blk % 40;
  const int h = (blk / 40) & 7;
  const int b = blk / 320;
  const int wv = threadIdx.x >> 6;     // strip 0..6, rows i in [50+16wv, 66+16wv)
  const int lane = threadIdx.x & 63;
  const int lo = lane & 15, hi = lane >> 4;

  __shared__ __align__(16) bf16_t E[7][16][40];  // per-wave 16x32 chunk (pad 40)

  const int i0 = 50 + 16 * wv;
  int jtmax = (65 + 16 * wv) >> 4;     // last 16-tile with any unmasked element
  if (jtmax > 9) jtmax = 9;
  const int reach = jtmax * 16 + 16;

  // Q fragment (pre-scaled by 1/sqrt(200)): row lo -> token t = n*100+16wv+lo
  int tq = n * 100 + 16 * wv + lo;
  if (tq > 3999) tq = 3999;            // rows i>=150 are discarded at store
  const bf16x8 qf = *(const bf16x8*)&qb[((size_t)b * 4000 + tq) * 256 + h * 32 + hi * 8];

  const f32x4 zero = {0.f, 0.f, 0.f, 0.f};
  bf16x8 onesf;
#pragma unroll
  for (int u = 0; u < 8; ++u) onesf[u] = (bf16_t)1.0f;

  f32x4 o0 = zero, o1 = zero, sm = zero;
  const size_t vbase = ((size_t)((b * 8 + h) * 32)) * 4064 + n * 100;
  const size_t kbase = ((size_t)(b * 4064 + n * 100)) * 256 + h * 32 + hi * 8;
  const int dbase = i0 + hi * 4 - lo;  // d = dbase + r - 16*jt

#pragma unroll
  for (int kt = 0; kt < 5; ++kt) if (kt * 32 < reach) {
    // two score tiles -> E chunk [16][32]
#pragma unroll
    for (int half = 0; half < 2; ++half) {
      const int jt = kt * 2 + half;
      if (jt <= jtmax) {
        const bf16x8 kf = *(const bf16x8*)&kb[kbase + (size_t)(jt * 16 + lo) * 256];
        const f32x4 s = MFMA16(qf, kf, zero);
#pragma unroll
        for (int r = 0; r < 4; ++r) {
          const int d = dbase + r - jt * 16;
          const float df = (float)d;
          float c = __builtin_amdgcn_rcpf(__builtin_fmaf(0.25f * df, df, 1.f));
          c = (d == 0) ? 0.f : c;      // eye-mask: diagonal score -> 0 -> e=1
          float e = __expf(s[r] * c);
          e = (d < 0) ? 0.f : e;       // causal mask
          E[wv][hi * 4 + r][half * 16 + lo] = (bf16_t)e;
        }
      } else {
#pragma unroll
        for (int r = 0; r < 4; ++r)
          E[wv][hi * 4 + r][half * 16 + lo] = (bf16_t)0.f;
      }
    }
    // PV + denom for this 32-col chunk (wave-private LDS, in-order DS)
    const bf16x8 pf = *(const bf16x8*)&E[wv][lo][hi * 8];
    const bf16x8 v0 = *(const bf16x8*)&vt[vbase + (size_t)lo * 4064 + kt * 32 + hi * 8];
    const bf16x8 v1 = *(const bf16x8*)&vt[vbase + (size_t)(16 + lo) * 4064 + kt * 32 + hi * 8];
    o0 = MFMA16(pf, v0, o0);
    o1 = MFMA16(pf, v1, o1);
    sm = MFMA16(pf, onesf, sm);
  }

  // store central rows (i in [50,150)): out = o * rcp(rowsum); rowsum >= 1
#pragma unroll
  for (int r = 0; r < 4; ++r) {
    const int i = i0 + hi * 4 + r;
    if (i < 150) {
      const float ri = __builtin_amdgcn_rcpf(sm[r]);
      const int t = n * 100 + i - 50;
      bf16_t* op = &ao[((size_t)b * 4000 + t) * 256 + h * 32];
      op[lo]      = (bf16_t)(o0[r] * ri);
      op[16 + lo] = (bf16_t)(o1[r] * ri);
    }
  }
}

// ---------------------------------------------------------------------------
extern "C" void kernel_launch(void* const* d_in, const int* in_sizes, int n_in,
                              void* d_out, int out_size, void* d_ws, size_t ws_size,
                              hipStream_t stream) {
  (void)in_sizes; (void)n_in; (void)out_size;
  const float* query = (const float*)d_in[0];
  const float* key   = (const float*)d_in[1];
  const float* value = (const float*)d_in[2];
  const float* Wq = (const float*)d_in[3];
  const float* bq = (const float*)d_in[4];
  const float* Wk = (const float*)d_in[5];
  const float* bk = (const float*)d_in[6];
  const float* Wv = (const float*)d_in[7];
  const float* bv = (const float*)d_in[8];
  const float* Wo = (const float*)d_in[9];
  const float* bo = (const float*)d_in[10];

  // pick largest batch chunk bc that fits ws_size:
  // bytes(bc) = 524288 (wt) + bc * 8,257,536 (qb+kb+vt+ao per batch)
  int bc = 8;
  while (bc > 1 && 524288ull + (unsigned long long)bc * 8257536ull > (unsigned long long)ws_size)
    bc >>= 1;

  bf16_t* wt = (bf16_t*)d_ws;                           // 4 * 65536
  bf16_t* qb = wt + 4 * 65536;                          // bc*4000*256
  bf16_t* kb = qb + (size_t)bc * 4000 * 256;            // bc*4064*256
  bf16_t* vt = kb + (size_t)bc * 4064 * 256;            // bc*8*32*4064
  bf16_t* ao = vt + (size_t)bc * 8 * 32 * 4064;         // bc*4000*256

  prep_weights<<<256, 256, 0, stream>>>(Wq, Wk, Wv, Wo, wt);

  const float qscale = 0.07071067811865475f;  // 1/sqrt(200) folded into qb

  for (int b0 = 0; b0 < 8; b0 += bc) {
    const int M = bc * 4000;
    const int mblk = (M + 63) / 64;
    const float* qx = query + (size_t)b0 * 4000 * 256;
    const float* kx = key   + (size_t)b0 * 4000 * 256;
    const float* vx = value + (size_t)b0 * 4000 * 256;
    float* ox = (float*)d_out + (size_t)b0 * 4000 * 256;

    proj_gemm<<<dim3(mblk, 3), 256, 0, stream>>>(qx, kx, vx, wt, bq, bk, bv,
                                                 qb, kb, vt, M, qscale);
    fill_edges<<<bc * 128, 256, 0, stream>>>(kb, vt, bc);
    attn_win<<<bc * 320, 448, 0, stream>>>(qb, kb, vt, ao);
    out_gemm<<<dim3(mblk), 256, 0, stream>>>(ao, wt + 3 * 65536, bo, ox, M);
  }
}

// Round 10
// 94.750 us; speedup vs baseline: 1.2610x; 1.2610x over previous
//
#include <hip/hip_runtime.h>

// ---------------------------------------------------------------------------
// MultiHeadAttentionWindow: B=8 K=4000 D=256 H=8 DQ=DV=32 WIN=200 PAD=50 STEP=100
// Pipeline (batch chunk bc from ws_size):
//   prep_weights : Wt[n][k] = bf16(W[k][n]) for Wq,Wk,Wv,Wo   (once)
//   per chunk:
//     proj_gemm  : merged q/k/v projections (grid.y = mode 0/1/2)
//     fill_edges : replicate-pad edges, zero tails
//     attn_win   : causal cauchy softmax windows, rows 50..149
//     out_gemm   : out = ao @ Wo + bo (fp32)
// Round-10 GEMM: r8 skeleton + global_load_lds (width 16) staging:
//   - A staged as FP32 direct-to-LDS (cvt on ds_read, overlapped with MFMA),
//     slot map s=(row,f), c4 = f ^ (row&7)  -> bank-floor fragment reads
//   - B staged direct-to-LDS linear [row][chunk16B]
//   - K-loop/wave: 6 gload_lds + 12 ds_read + 16 MFMA + 2 barriers
//   (r9's B-in-regs spilled: VGPR_Count=96 < required 128+64 -> reverted)
// ---------------------------------------------------------------------------

typedef __bf16 bf16_t;
typedef __bf16 bf16x8 __attribute__((ext_vector_type(8)));
typedef float  f32x4  __attribute__((ext_vector_type(4)));

#define MFMA16(a, b, c) __builtin_amdgcn_mfma_f32_16x16x32_bf16((a), (b), (c), 0, 0, 0)

typedef __attribute__((address_space(1))) const unsigned char gas_u8;
typedef __attribute__((address_space(3))) unsigned char las_u8;

static __device__ __forceinline__ void gload16(const void* g, void* l) {
  __builtin_amdgcn_global_load_lds((gas_u8*)g, (las_u8*)l, 16, 0, 0);
}

static __device__ __forceinline__ bf16x8 cvt8(float4 a, float4 b) {
  bf16x8 r;
  r[0] = (bf16_t)a.x; r[1] = (bf16_t)a.y; r[2] = (bf16_t)a.z; r[3] = (bf16_t)a.w;
  r[4] = (bf16_t)b.x; r[5] = (bf16_t)b.y; r[6] = (bf16_t)b.z; r[7] = (bf16_t)b.w;
  return r;
}

static __device__ __forceinline__ unsigned short bbits(bf16_t v) {
  union { bf16_t b; unsigned short u; } c; c.b = v; return c.u;
}

// ---- weight transpose + bf16 convert: Wt[n][k] = bf16(W[k][n]), 4 matrices ----
__global__ __launch_bounds__(256)
void prep_weights(const float* __restrict__ Wq, const float* __restrict__ Wk,
                  const float* __restrict__ Wv, const float* __restrict__ Wo,
                  bf16_t* __restrict__ wt) {
  const int mat  = blockIdx.x >> 6;
  const int tile = blockIdx.x & 63;
  const int kt = (tile >> 3) * 32, nt = (tile & 7) * 32;
  const float* W = (mat == 0) ? Wq : (mat == 1) ? Wk : (mat == 2) ? Wv : Wo;
  __shared__ float t[32][33];
  const int tx = threadIdx.x & 31, ty = threadIdx.x >> 5;  // ty 0..7
#pragma unroll
  for (int i = 0; i < 32; i += 8)
    t[ty + i][tx] = W[(size_t)(kt + ty + i) * 256 + nt + tx];
  __syncthreads();
  bf16_t* dst = wt + (size_t)mat * 65536;
#pragma unroll
  for (int i = 0; i < 32; i += 8)
    dst[(size_t)(nt + ty + i) * 256 + kt + tx] = (bf16_t)t[tx][ty + i];
}

// ---- merged projection GEMM: [M x 256] x [256 x 256] + bias ----
// grid (mblk, 3); mode = blockIdx.y: 0 -> qb (row-major, *qscale),
// 1 -> kb (rows b*4064+t+50), 2 -> vt (transposed [bh*32+dv][p]).
// Block: 64 rows x 256 cols, 4 waves; wave = 64 rows x 64-col slice.
__global__ __launch_bounds__(256)
void proj_gemm(const float* __restrict__ qx, const float* __restrict__ kx,
               const float* __restrict__ vx, const bf16_t* __restrict__ wt,
               const float* __restrict__ bq, const float* __restrict__ bk,
               const float* __restrict__ bv,
               bf16_t* __restrict__ qb, bf16_t* __restrict__ kb,
               bf16_t* __restrict__ vt, int M, float qscale) {
  const int mode = blockIdx.y;
  const float* X    = (mode == 0) ? qx : (mode == 1) ? kx : vx;
  const float* bias = (mode == 0) ? bq : (mode == 1) ? bk : bv;
  const bf16_t* W   = wt + (size_t)mode * 65536;

  // LDS: A region 8KB (512 slots x 16B, fp32), B region 16KB (1024 slots, bf16)
  __shared__ __align__(16) char lds[8192 + 16384];
  char* ldsA = lds;
  char* ldsB = lds + 8192;

  const int tid  = threadIdx.x;
  const int lane = tid & 63;
  const int w    = tid >> 6;        // wave 0..3 (n-slice wn = w*64)
  const int lo   = lane & 15, hi = lane >> 4;
  const int m0   = blockIdx.x * 64;

  // A staging sources: issue j in {0,1}: slot s=(w*2+j)*64+lane; row=s>>3,
  // f=s&7, c4 = f ^ (row&7). src = X[(m0+row)*256 + kk*32 + c4*4]
  const float* asrc[2];
  char* aldst[2];
#pragma unroll
  for (int j = 0; j < 2; ++j) {
    const int s = (w * 2 + j) * 64 + lane;
    const int row = s >> 3, f = s & 7;
    const int ar = (m0 + row < M) ? (m0 + row) : (M - 1);
    asrc[j]  = X + (size_t)ar * 256 + ((f ^ (row & 7)) << 2);
    aldst[j] = ldsA + (w * 2 + j) * 1024;
  }
  // B staging: issue j in {0..3}: slot s=(w*4+j)*64+lane; row=s>>2, ch=s&3.
  const bf16_t* bsrc[4];
  char* bldst[4];
#pragma unroll
  for (int j = 0; j < 4; ++j) {
    const int s = (w * 4 + j) * 64 + lane;
    bsrc[j]  = W + (size_t)(s >> 2) * 256 + ((s & 3) << 3);
    bldst[j] = ldsB + (w * 4 + j) * 1024;
  }
  // fragment read bases
  int abase[4], bbase[4];
#pragma unroll
  for (int mi = 0; mi < 4; ++mi)
    abase[mi] = (((mi * 16 + lo) << 3) + ((2 * hi) ^ (lo & 7))) << 4;
#pragma unroll
  for (int ni = 0; ni < 4; ++ni)
    bbase[ni] = (w * 64 + ni * 16 + lo) * 64 + hi * 16;

  f32x4 acc[4][4] = {};

  for (int kk = 0; kk < 8; ++kk) {
#pragma unroll
    for (int j = 0; j < 2; ++j) gload16(asrc[j] + kk * 32, aldst[j]);
#pragma unroll
    for (int j = 0; j < 4; ++j) gload16(bsrc[j] + kk * 32, bldst[j]);
    __syncthreads();                 // drains vmcnt -> tiles landed

    bf16x8 af[4], bfv[4];
#pragma unroll
    for (int mi = 0; mi < 4; ++mi) {
      const float4 v0 = *(const float4*)(ldsA + abase[mi]);
      const float4 v1 = *(const float4*)(ldsA + (abase[mi] ^ 16));
      af[mi] = cvt8(v0, v1);         // v0 = c4 even half (k 0..3), v1 = +4
    }
#pragma unroll
    for (int ni = 0; ni < 4; ++ni)
      bfv[ni] = *(const bf16x8*)(ldsB + bbase[ni]);
#pragma unroll
    for (int mi = 0; mi < 4; ++mi)
#pragma unroll
      for (int ni = 0; ni < 4; ++ni)
        acc[mi][ni] = MFMA16(af[mi], bfv[ni], acc[mi][ni]);
    __syncthreads();                 // protect tiles from next-iter overwrite
  }

  // epilogue: C/D layout col = lane&15, row = (lane>>4)*4 + r  [m89-verified]
#pragma unroll
  for (int mi = 0; mi < 4; ++mi) {
    const int mb = m0 + mi * 16 + hi * 4;   // 4-aligned; M % 4 == 0
    if (mb >= M) continue;
#pragma unroll
    for (int ni = 0; ni < 4; ++ni) {
      const int n = w * 64 + ni * 16 + lo;
      const float bia = bias[n];
      if (mode == 0) {
#pragma unroll
        for (int rr = 0; rr < 4; ++rr)
          qb[(size_t)(mb + rr) * 256 + n] = (bf16_t)((acc[mi][ni][rr] + bia) * qscale);
      } else if (mode == 1) {
        const int b = mb / 4000, t = mb - b * 4000;
#pragma unroll
        for (int rr = 0; rr < 4; ++rr)
          kb[((size_t)b * 4064 + t + 50 + rr) * 256 + n] = (bf16_t)(acc[mi][ni][rr] + bia);
      } else {
        const int b = mb / 4000, t = mb - b * 4000;
        const int h = n >> 5, dv = n & 31;
        bf16_t* O = vt + ((size_t)((b * 8 + h) * 32 + dv)) * 4064 + t + 50;
        unsigned short e0 = bbits((bf16_t)(acc[mi][ni][0] + bia));
        unsigned short e1 = bbits((bf16_t)(acc[mi][ni][1] + bia));
        unsigned short e2 = bbits((bf16_t)(acc[mi][ni][2] + bia));
        unsigned short e3 = bbits((bf16_t)(acc[mi][ni][3] + bia));
        unsigned* O32 = (unsigned*)O;       // (t+50) even -> 4B aligned
        O32[0] = (unsigned)e0 | ((unsigned)e1 << 16);
        O32[1] = (unsigned)e2 | ((unsigned)e3 << 16);
      }
    }
  }
}

// ---- output GEMM: ao[M x 256] (bf16) x Wo^T + bo -> fp32 out ----
__global__ __launch_bounds__(256)
void out_gemm(const bf16_t* __restrict__ ao, const bf16_t* __restrict__ wt,
              const float* __restrict__ bias, float* __restrict__ Out, int M) {
  // LDS: A region 4KB (256 slots, bf16 linear), B region 16KB
  __shared__ __align__(16) char lds[4096 + 16384];
  char* ldsA = lds;
  char* ldsB = lds + 4096;

  const int tid  = threadIdx.x;
  const int lane = tid & 63;
  const int w    = tid >> 6;
  const int lo   = lane & 15, hi = lane >> 4;
  const int m0   = blockIdx.x * 64;

  // A: 1 issue/wave: slot s = w*64+lane; row=s>>2, ch=s&3 (16B of 8 bf16)
  const bf16_t* asrc;
  char* aldst;
  {
    const int s = w * 64 + lane;
    const int row = s >> 2;
    const int ar = (m0 + row < M) ? (m0 + row) : (M - 1);
    asrc  = ao + (size_t)ar * 256 + ((s & 3) << 3);
    aldst = ldsA + w * 1024;
  }
  const bf16_t* bsrc[4];
  char* bldst[4];
#pragma unroll
  for (int j = 0; j < 4; ++j) {
    const int s = (w * 4 + j) * 64 + lane;
    bsrc[j]  = wt + (size_t)(s >> 2) * 256 + ((s & 3) << 3);
    bldst[j] = ldsB + (w * 4 + j) * 1024;
  }
  int abase[4], bbase[4];
#pragma unroll
  for (int mi = 0; mi < 4; ++mi)
    abase[mi] = (mi * 16 + lo) * 64 + hi * 16;
#pragma unroll
  for (int ni = 0; ni < 4; ++ni)
    bbase[ni] = (w * 64 + ni * 16 + lo) * 64 + hi * 16;

  f32x4 acc[4][4] = {};

  for (int kk = 0; kk < 8; ++kk) {
    gload16(asrc + kk * 32, aldst);
#pragma unroll
    for (int j = 0; j < 4; ++j) gload16(bsrc[j] + kk * 32, bldst[j]);
    __syncthreads();

    bf16x8 af[4], bfv[4];
#pragma unroll
    for (int mi = 0; mi < 4; ++mi)
      af[mi] = *(const bf16x8*)(ldsA + abase[mi]);
#pragma unroll
    for (int ni = 0; ni < 4; ++ni)
      bfv[ni] = *(const bf16x8*)(ldsB + bbase[ni]);
#pragma unroll
    for (int mi = 0; mi < 4; ++mi)
#pragma unroll
      for (int ni = 0; ni < 4; ++ni)
        acc[mi][ni] = MFMA16(af[mi], bfv[ni], acc[mi][ni]);
    __syncthreads();
  }

#pragma unroll
  for (int mi = 0; mi < 4; ++mi) {
    const int mb = m0 + mi * 16 + hi * 4;
    if (mb >= M) continue;
#pragma unroll
    for (int ni = 0; ni < 4; ++ni) {
      const int n = w * 64 + ni * 16 + lo;
      const float bia = bias[n];
#pragma unroll
      for (int rr = 0; rr < 4; ++rr)
        Out[(size_t)(mb + rr) * 256 + n] = acc[mi][ni][rr] + bia;
    }
  }
}

// ---- fill replicate-pad edges + zero tails for kb and vt (nb batches) ----
__global__ void fill_edges(bf16_t* __restrict__ kb, bf16_t* __restrict__ vt, int nb) {
  const int idx = blockIdx.x * 256 + threadIdx.x;
  const int kcnt = nb * 64 * 256;
  if (idx < kcnt) {                    // kb: [nb][4064][256]
    const int b  = idx >> 14;
    const int pp = (idx >> 8) & 63;    // 0..63
    const int nn = idx & 255;
    const int p  = (pp < 50) ? pp : pp + 4000;   // [0,50) and [4050,4064)
    bf16_t v = (pp < 50) ? kb[((size_t)b * 4064 + 50) * 256 + nn] : (bf16_t)0.f;
    kb[((size_t)b * 4064 + p) * 256 + nn] = v;
  } else {                             // vt: [nb*8][32][4064]
    const int j  = idx - kcnt;
    const int bh = j >> 11;
    const int dv = (j >> 6) & 31;
    const int pp = j & 63;
    const int p  = (pp < 50) ? pp : pp + 4000;
    bf16_t v = (pp < 50) ? vt[((size_t)bh * 32 + dv) * 4064 + 50] : (bf16_t)0.f;
    vt[((size_t)bh * 32 + dv) * 4064 + p] = v;
  }
}

// ---- windowed attention: one block per (b',h,window), 7 waves = 7 row-strips ----
// Chunked: per 32-col chunk {2x QK MFMA -> exp -> 16x32 LDS bounce -> PV 3 MFMA}.
// No cross-lane ops, no barriers; denom via E@ones; normalize after PV.
__global__ __launch_bounds__(448)
void attn_win(const bf16_t* __restrict__ qb, const bf16_t* __restrict__ kb,
              const bf16_t* __restrict__ vt, bf16_t* __restrict__ ao) {
  const int blk = blockIdx.x;
  const int n = blk % 40;
  const int h = (blk / 40) & 7;
  const int b = blk / 320;
  const int wv = threadIdx.x >> 6;     // strip 0..6, rows i in [50+16wv, 66+16wv)
  const int lane = threadIdx.x & 63;
  const int lo = lane & 15, hi = lane >> 4;

  __shared__ __align__(16) bf16_t E[7][16][40];  // per-wave 16x32 chunk (pad 40)

  const int i0 = 50 + 16 * wv;
  int jtmax = (65 + 16 * wv) >> 4;     // last 16-tile with any unmasked element
  if (jtmax > 9) jtmax = 9;
  const int reach = jtmax * 16 + 16;

  // Q fragment (pre-scaled by 1/sqrt(200)): row lo -> token t = n*100+16wv+lo
  int tq = n * 100 + 16 * wv + lo;
  if (tq > 3999) tq = 3999;            // rows i>=150 are discarded at store
  const bf16x8 qf = *(const bf16x8*)&qb[((size_t)b * 4000 + tq) * 256 + h * 32 + hi * 8];

  const f32x4 zero = {0.f, 0.f, 0.f, 0.f};
  bf16x8 onesf;
#pragma unroll
  for (int u = 0; u < 8; ++u) onesf[u] = (bf16_t)1.0f;

  f32x4 o0 = zero, o1 = zero, sm = zero;
  const size_t vbase = ((size_t)((b * 8 + h) * 32)) * 4064 + n * 100;
  const size_t kbase = ((size_t)(b * 4064 + n * 100)) * 256 + h * 32 + hi * 8;
  const int dbase = i0 + hi * 4 - lo;  // d = dbase + r - 16*jt

#pragma unroll
  for (int kt = 0; kt < 5; ++kt) if (kt * 32 < reach) {
    // two score tiles -> E chunk [16][32]
#pragma unroll
    for (int half = 0; half < 2; ++half) {
      const int jt = kt * 2 + half;
      if (jt <= jtmax) {
        const bf16x8 kf = *(const bf16x8*)&kb[kbase + (size_t)(jt * 16 + lo) * 256];
        const f32x4 s = MFMA16(qf, kf, zero);
#pragma unroll
        for (int r = 0; r < 4; ++r) {
          const int d = dbase + r - jt * 16;
          const float df = (float)d;
          float c = __builtin_amdgcn_rcpf(__builtin_fmaf(0.25f * df, df, 1.f));
          c = (d == 0) ? 0.f : c;      // eye-mask: diagonal score -> 0 -> e=1
          float e = __expf(s[r] * c);
          e = (d < 0) ? 0.f : e;       // causal mask
          E[wv][hi * 4 + r][half * 16 + lo] = (bf16_t)e;
        }
      } else {
#pragma unroll
        for (int r = 0; r < 4; ++r)
          E[wv][hi * 4 + r][half * 16 + lo] = (bf16_t)0.f;
      }
    }
    // PV + denom for this 32-col chunk (wave-private LDS, in-order DS)
    const bf16x8 pf = *(const bf16x8*)&E[wv][lo][hi * 8];
    const bf16x8 v0 = *(const bf16x8*)&vt[vbase + (size_t)lo * 4064 + kt * 32 + hi * 8];
    const bf16x8 v1 = *(const bf16x8*)&vt[vbase + (size_t)(16 + lo) * 4064 + kt * 32 + hi * 8];
    o0 = MFMA16(pf, v0, o0);
    o1 = MFMA16(pf, v1, o1);
    sm = MFMA16(pf, onesf, sm);
  }

  // store central rows (i in [50,150)): out = o * rcp(rowsum); rowsum >= 1
#pragma unroll
  for (int r = 0; r < 4; ++r) {
    const int i = i0 + hi * 4 + r;
    if (i < 150) {
      const float ri = __builtin_amdgcn_rcpf(sm[r]);
      const int t = n * 100 + i - 50;
      bf16_t* op = &ao[((size_t)b * 4000 + t) * 256 + h * 32];
      op[lo]      = (bf16_t)(o0[r] * ri);
      op[16 + lo] = (bf16_t)(o1[r] * ri);
    }
  }
}

// ---------------------------------------------------------------------------
extern "C" void kernel_launch(void* const* d_in, const int* in_sizes, int n_in,
                              void* d_out, int out_size, void* d_ws, size_t ws_size,
                              hipStream_t stream) {
  (void)in_sizes; (void)n_in; (void)out_size;
  const float* query = (const float*)d_in[0];
  const float* key   = (const float*)d_in[1];
  const float* value = (const float*)d_in[2];
  const float* Wq = (const float*)d_in[3];
  const float* bq = (const float*)d_in[4];
  const float* Wk = (const float*)d_in[5];
  const float* bk = (const float*)d_in[6];
  const float* Wv = (const float*)d_in[7];
  const float* bv = (const float*)d_in[8];
  const float* Wo = (const float*)d_in[9];
  const float* bo = (const float*)d_in[10];

  // pick largest batch chunk bc that fits ws_size:
  // bytes(bc) = 524288 (wt) + bc * 8,257,536 (qb+kb+vt+ao per batch)
  int bc = 8;
  while (bc > 1 && 524288ull + (unsigned long long)bc * 8257536ull > (unsigned long long)ws_size)
    bc >>= 1;

  bf16_t* wt = (bf16_t*)d_ws;                           // 4 * 65536
  bf16_t* qb = wt + 4 * 65536;                          // bc*4000*256
  bf16_t* kb = qb + (size_t)bc * 4000 * 256;            // bc*4064*256
  bf16_t* vt = kb + (size_t)bc * 4064 * 256;            // bc*8*32*4064
  bf16_t* ao = vt + (size_t)bc * 8 * 32 * 4064;         // bc*4000*256

  prep_weights<<<256, 256, 0, stream>>>(Wq, Wk, Wv, Wo, wt);

  const float qscale = 0.07071067811865475f;  // 1/sqrt(200) folded into qb

  for (int b0 = 0; b0 < 8; b0 += bc) {
    const int M = bc * 4000;
    const int mblk = (M + 63) / 64;
    const float* qx = query + (size_t)b0 * 4000 * 256;
    const float* kx = key   + (size_t)b0 * 4000 * 256;
    const float* vx = value + (size_t)b0 * 4000 * 256;
    float* ox = (float*)d_out + (size_t)b0 * 4000 * 256;

    proj_gemm<<<dim3(mblk, 3), 256, 0, stream>>>(qx, kx, vx, wt, bq, bk, bv,
                                                 qb, kb, vt, M, qscale);
    fill_edges<<<bc * 128, 256, 0, stream>>>(kb, vt, bc);
    attn_win<<<bc * 320, 448, 0, stream>>>(qb, kb, vt, ao);
    out_gemm<<<dim3(mblk), 256, 0, stream>>>(ao, wt + 3 * 65536, bo, ox, M);
  }
}